// Round 7
// baseline (550.747 us; speedup 1.0000x reference)
//
#include <hip/hip_runtime.h>
#include <hip/hip_bf16.h>

#define V_ 262144
#define B_ 4
#define C_ 16
#define F_ 64
#define K_ 100
#define CAP_ 8192

// ---- ws layout (bytes) ----
#define OFF_WEIGHTS 0
#define OFF_LABELS  4194304
#define OFF_ZERO    5242880
#define OFF_HIST    5242880
#define OFF_CNT     5275648
#define OFF_SUMS    5275712
#define OFF_CCNT    5279808
#define ZERO_BYTES  36944
#define OFF_THRESH  5279824
#define OFF_CVAL    5279840
#define OFF_CIDX    5410912

// K1 (UNCHANGED — control): weights = prod_c proba; labels = argmax_c y;
// class counts; topk hist. 2048-voxel span, grid (V/2048, B).
__global__ __launch_bounds__(256) void k_stream(const float* __restrict__ proba,
                                                const float* __restrict__ y,
                                                float* __restrict__ weights,
                                                unsigned char* __restrict__ labels,
                                                int* __restrict__ hist,
                                                int* __restrict__ cnt)
{
    const int b = blockIdx.y;
    const int tid = threadIdx.x;
    const int q = blockIdx.x * 512 + tid;   // float4 index within batch

    __shared__ int lhist[2048];
    __shared__ int lcnt[16];
    for (int i = tid; i < 2048; i += 256) lhist[i] = 0;
    if (tid < 16) lcnt[tid] = 0;
    __syncthreads();

    const float4* pb = (const float4*)(proba + ((size_t)b * C_) * V_) + q;
    const float4* yb = (const float4*)(y     + ((size_t)b * C_) * V_) + q;
    const int s4 = V_ >> 2;                 // float4 stride between c-rows

    float4 p0 = pb[0], p1 = pb[256];        // c = 0 product init
    int4 l0 = make_int4(0, 0, 0, 0);        // label stays 0 if hot at c=0
    int4 l1 = make_int4(0, 0, 0, 0);

    #pragma unroll
    for (int c = 1; c < C_; c++) {
        float4 a0 = pb[c * s4], a1 = pb[c * s4 + 256];
        float4 q0 = yb[c * s4], q1 = yb[c * s4 + 256];
        p0.x *= a0.x; p0.y *= a0.y; p0.z *= a0.z; p0.w *= a0.w;
        p1.x *= a1.x; p1.y *= a1.y; p1.z *= a1.z; p1.w *= a1.w;
        if (q0.x > 0.f) l0.x = c;
        if (q0.y > 0.f) l0.y = c;
        if (q0.z > 0.f) l0.z = c;
        if (q0.w > 0.f) l0.w = c;
        if (q1.x > 0.f) l1.x = c;
        if (q1.y > 0.f) l1.y = c;
        if (q1.z > 0.f) l1.z = c;
        if (q1.w > 0.f) l1.w = c;
    }

    float4* wout = (float4*)(weights + (size_t)b * V_);
    wout[q] = p0; wout[q + 256] = p1;
    uchar4* lout = (uchar4*)(labels + (size_t)b * V_);
    lout[q]       = make_uchar4((unsigned char)l0.x, (unsigned char)l0.y,
                                (unsigned char)l0.z, (unsigned char)l0.w);
    lout[q + 256] = make_uchar4((unsigned char)l1.x, (unsigned char)l1.y,
                                (unsigned char)l1.z, (unsigned char)l1.w);

    float wv[8] = {p0.x, p0.y, p0.z, p0.w, p1.x, p1.y, p1.z, p1.w};
    int   lv[8] = {l0.x, l0.y, l0.z, l0.w, l1.x, l1.y, l1.z, l1.w};
    #pragma unroll
    for (int j = 0; j < 8; j++) {
        atomicAdd(&lcnt[lv[j]], 1);
        atomicAdd(&lhist[__float_as_uint(wv[j]) >> 21], 1);
    }
    __syncthreads();
    if (tid < 16) atomicAdd(&cnt[tid], lcnt[tid]);
    for (int i = tid; i < 2048; i += 256)
        if (lhist[i]) atomicAdd(&hist[b * 2048 + i], lhist[i]);
}

// K2 LABEL-AMORTIZATION: fabric traffic was 512 MB (256 emb + 256 label
// re-reads: 1 MB label row x 64 f-readers, L2/L3-served so invisible in
// FETCH_SIZE) at 5.1 TB/s = the structure-invariant ~100 us. Block = 512
// threads = 8 subgroups x 64 lanes over 8 f-rows of one (b, segment); the
// segment's 32 KB label slice is staged into LDS ONCE and shared by all 8
// rows -> label traffic /8, total 288 MB. Atomic-free VGPR select-add.
// grid (8 seg, 8 fgroup, B).
__global__ __launch_bounds__(512) void k_sums(const float* __restrict__ emb,
                                              const unsigned char* __restrict__ labels,
                                              float* __restrict__ sums)
{
    __shared__ unsigned int slab[8192];      // 32 KB: labels for 32768 voxels
    __shared__ float lacc[512 * 17];         // per-thread private spill slots
    __shared__ float part[512];
    const int tid  = threadIdx.x;
    const int lane = tid & 63;
    const int sg   = tid >> 6;              // 0..7 : f offset within group

    const int seg = blockIdx.x;             // 0..7
    const int fg  = blockIdx.y;             // 0..7
    const int b   = blockIdx.z;             // 0..3
    const int f   = (fg << 3) + sg;
    const int vlen = V_ / 8;                // 32768 voxels per segment

    // stage segment labels into LDS once (coalesced uint4 loads)
    {
        const uint4* lg = (const uint4*)(labels + (size_t)b * V_ + (size_t)seg * vlen);
        uint4* sl4 = (uint4*)slab;
        #pragma unroll
        for (int i = 0; i < 4; i++)         // 2048 uint4 / 512 threads
            sl4[i * 512 + tid] = lg[i * 512 + tid];
    }
    __syncthreads();

    const float4* src = (const float4*)(emb + (((size_t)b << 6) + f) * V_
                                        + (size_t)seg * vlen);

    float acc[16];
    #pragma unroll
    for (int c = 0; c < 16; c++) acc[c] = 0.f;

    // 8192 float4 per row-segment / 64 lanes = 128 per lane; batches of 8
    for (int it = 0; it < 16; it++) {
        float4 v[8];
        unsigned lu[8];
        #pragma unroll
        for (int g = 0; g < 8; g++) {
            const int i4 = it * 512 + g * 64 + lane;
            v[g]  = src[i4];
            lu[g] = slab[i4];               // consecutive dwords: 2-way = free
        }
        __builtin_amdgcn_sched_barrier(0);   // keep the 8 global loads clustered
        #pragma unroll
        for (int g = 0; g < 8; g++) {
            const int l0 =  lu[g]        & 0xff;
            const int l1 = (lu[g] >>  8) & 0xff;
            const int l2 = (lu[g] >> 16) & 0xff;
            const int l3 =  lu[g] >> 24;
            #pragma unroll
            for (int c = 0; c < 16; c++) {
                float s = (l0 == c ? v[g].x : 0.f);
                s      += (l1 == c ? v[g].y : 0.f);
                s      += (l2 == c ? v[g].z : 0.f);
                s      += (l3 == c ? v[g].w : 0.f);
                acc[c] += s;
            }
        }
    }

    // spill to private LDS slots (stride 17 = conflict-free), reduce PER SUBGROUP
    #pragma unroll
    for (int c = 0; c < 16; c++) lacc[tid * 17 + c] = acc[c];
    __syncthreads();
    {
        const int c    = tid & 15;
        const int rgrp = (tid >> 4) & 3;
        const int sgg  = tid >> 6;
        float s = 0.f;
        #pragma unroll
        for (int i = 0; i < 16; i++)
            s += lacc[((sgg << 6) + (rgrp << 4) + i) * 17 + c];
        part[tid] = s;
    }
    __syncthreads();
    if ((tid & 48) == 0) {                  // rgrp == 0: one thread per (sg, c)
        const int c   = tid & 15;
        const int sgg = tid >> 6;
        float s = part[(sgg << 6) + c]      + part[(sgg << 6) + 16 + c]
                + part[(sgg << 6) + 32 + c] + part[(sgg << 6) + 48 + c];
        atomicAdd(&sums[(c << 6) + (fg << 3) + sgg], s);
    }
}

// K4 (absorbs K3): recompute per-batch threshold bin T from the L2-resident
// 8 KB histogram inside every block, then collect candidates with bin >= T.
__global__ __launch_bounds__(256) void k_collect(const float* __restrict__ weights,
                                                 const int* __restrict__ hist,
                                                 int* __restrict__ ccnt,
                                                 float* __restrict__ cval,
                                                 int* __restrict__ cidx)
{
    const int b = blockIdx.y;
    const int tid = threadIdx.x;
    __shared__ int part[256];
    __shared__ int suf[257];
    __shared__ int sT;

    const int* h = hist + b * 2048;
    int loc[8]; int s = 0;
    #pragma unroll
    for (int i = 0; i < 8; i++) { loc[i] = h[tid * 8 + i]; s += loc[i]; }
    part[tid] = s;
    __syncthreads();
    if (tid == 0) {
        suf[256] = 0;
        for (int t = 255; t >= 0; t--) suf[t] = suf[t + 1] + part[t];
    }
    __syncthreads();
    int cg[9];
    cg[8] = suf[tid + 1];
    #pragma unroll
    for (int i = 7; i >= 0; i--) cg[i] = cg[i + 1] + loc[i];
    #pragma unroll
    for (int i = 0; i < 8; i++)
        if (cg[i] >= K_ && cg[i + 1] < K_) sT = tid * 8 + i;
    __syncthreads();

    const unsigned T = (unsigned)sT;
    const int v = (blockIdx.x * 256 + tid) * 4;
    float4 w = *(const float4*)(weights + (size_t)b * V_ + v);
    float wv[4] = {w.x, w.y, w.z, w.w};
    for (int j = 0; j < 4; j++) {
        unsigned bits = __float_as_uint(wv[j]);
        if ((bits >> 21) >= T) {
            int p = atomicAdd(&ccnt[b], 1);
            if (p < CAP_) {
                cval[b * CAP_ + p] = wv[j];
                cidx[b * CAP_ + p] = v + j;
            }
        }
    }
}

// K5: exact top-K select, gather he/hec, build avg, pairwise contrastive loss.
__global__ __launch_bounds__(256) void k_final(const float* __restrict__ emb,
                                               const unsigned char* __restrict__ labels,
                                               const float* __restrict__ sums,
                                               const int* __restrict__ cnt,
                                               const int* __restrict__ ccnt,
                                               const float* __restrict__ cval,
                                               const int* __restrict__ cidx,
                                               float* __restrict__ out)
{
    const int b = blockIdx.x, tid = threadIdx.x;
    __shared__ float avg[1024];
    __shared__ float ec[K_ * 64];
    __shared__ float Ssum[K_ * 64];
    __shared__ float lsum[K_];
    __shared__ int selIdx[K_];
    __shared__ int selLab[K_];
    __shared__ int nk[16];
    __shared__ int lists[16 * K_];
    __shared__ int ofs[17];
    __shared__ float red[256];

    for (int i = tid; i < 1024; i += 256) {
        int c = i >> 6;
        float cn = (float)cnt[c];
        avg[i] = (cn > 0.f) ? 0.9f * sums[i] / fmaxf(cn, 1.f) : 0.f;
    }
    if (tid < K_) { lsum[tid] = 0.f; selIdx[tid] = 0; }
    if (tid < 16) nk[tid] = 0;

    int M = ccnt[b]; if (M > CAP_) M = CAP_;
    const float* cv = cval + b * CAP_;
    const int*   ci = cidx + b * CAP_;
    for (int i = tid; i < M; i += 256) {
        float v = cv[i]; int id = ci[i];
        int rank = 0;
        for (int j = 0; j < M; j++) {
            float vj = cv[j];
            rank += (vj > v) || (vj == v && ci[j] < id);
        }
        if (rank < K_) selIdx[rank] = id;
    }
    __syncthreads();
    for (int i = tid; i < K_; i += 256) selLab[i] = labels[(size_t)b * V_ + selIdx[i]];
    __syncthreads();
    if (tid == 0) {
        for (int i = 0; i < K_; i++) { int c = selLab[i]; lists[c * K_ + nk[c]] = i; nk[c]++; }
        int o = 0;
        for (int c = 0; c < 16; c++) { ofs[c] = o; o += nk[c] * nk[c]; }
        ofs[16] = o;
    }
    __syncthreads();

    for (int e = tid; e < K_ * 64; e += 256) {
        int k = e >> 6, f = e & 63;
        float h = emb[(((size_t)b << 6) + f) * V_ + selIdx[k]];
        int lab = selLab[k];
        float s = 0.f, ev = 0.f, lvv = 0.f;
        for (int c = 0; c < 16; c++) {
            float l = h * avg[(c << 6) + f] / 0.1f;
            float x = expf(l);
            s += x;
            if (c == lab) { ev = x; lvv = l; }
        }
        ec[e] = ev; Ssum[e] = s;
        atomicAdd(&lsum[k], lvv);
    }
    __syncthreads();

    const int P = ofs[16];
    float accv = 0.f;
    for (int p = tid; p < P; p += 256) {
        int c = 0;
        while (p >= ofs[c + 1]) c++;
        int loc = p - ofs[c];
        int n = nk[c];
        int i = lists[c * K_ + loc / n];
        int j = lists[c * K_ + loc % n];
        const float* eci = &ec[i << 6];
        const float* ecj = &ec[j << 6];
        const float* sj  = &Ssum[j << 6];
        float s = 0.f;
        for (int f = 0; f < 64; f++) s += logf(eci[f] + sj[f] - ecj[f]);
        accv += s / ((float)n * (float)n * 64.f);
    }
    for (int i2 = tid; i2 < K_; i2 += 256) {
        int c = selLab[i2];
        accv -= lsum[i2] / ((float)nk[c] * 64.f);
    }
    red[tid] = accv;
    __syncthreads();
    for (int s2 = 128; s2 > 0; s2 >>= 1) {
        if (tid < s2) red[tid] += red[tid + s2];
        __syncthreads();
    }
    if (tid == 0) atomicAdd(out, -red[0] / (float)B_);
}

extern "C" void kernel_launch(void* const* d_in, const int* in_sizes, int n_in,
                              void* d_out, int out_size, void* d_ws, size_t ws_size,
                              hipStream_t stream) {
    const float* proba = (const float*)d_in[0];
    const float* y     = (const float*)d_in[1];
    const float* emb   = (const float*)d_in[2];
    char* ws = (char*)d_ws;

    float* weights        = (float*)(ws + OFF_WEIGHTS);
    unsigned char* labels = (unsigned char*)(ws + OFF_LABELS);
    int* hist             = (int*)(ws + OFF_HIST);
    int* cnt              = (int*)(ws + OFF_CNT);
    float* sums           = (float*)(ws + OFF_SUMS);
    int* ccnt             = (int*)(ws + OFF_CCNT);
    float* cval           = (float*)(ws + OFF_CVAL);
    int* cidx             = (int*)(ws + OFF_CIDX);
    float* out            = (float*)d_out;

    hipMemsetAsync(ws + OFF_ZERO, 0, ZERO_BYTES, stream);
    hipMemsetAsync(out, 0, sizeof(float), stream);

    k_stream<<<dim3(V_ / 2048, B_), 256, 0, stream>>>(proba, y, weights, labels, hist, cnt);
    k_sums<<<dim3(8, 8, B_), 512, 0, stream>>>(emb, labels, sums);
    k_collect<<<dim3(V_ / 1024, B_), 256, 0, stream>>>(weights, hist, ccnt, cval, cidx);
    k_final<<<B_, 256, 0, stream>>>(emb, labels, sums, cnt, ccnt, cval, cidx, out);
}

// Round 8
// 518.641 us; speedup vs baseline: 1.0619x; 1.0619x over previous
//
#include <hip/hip_runtime.h>
#include <hip/hip_bf16.h>

#define V_ 262144
#define B_ 4
#define C_ 16
#define F_ 64
#define K_ 100
#define CAP_ 8192
#define SEG_ 8   // emb row segments in k_sums

// ---- ws layout (bytes) ----
#define OFF_WEIGHTS 0
#define OFF_LABELS  4194304
#define OFF_ZERO    5242880
#define OFF_HIST    5242880
#define OFF_CNT     5275648
#define OFF_SUMS    5275712
#define OFF_CCNT    5279808
#define ZERO_BYTES  36944
#define OFF_THRESH  5279824
#define OFF_CVAL    5279840
#define OFF_CIDX    5410912

// K1 (UNCHANGED — control): weights = prod_c proba; labels = argmax_c y;
// class counts; topk hist. 2048-voxel span, grid (V/2048, B).
__global__ __launch_bounds__(256) void k_stream(const float* __restrict__ proba,
                                                const float* __restrict__ y,
                                                float* __restrict__ weights,
                                                unsigned char* __restrict__ labels,
                                                int* __restrict__ hist,
                                                int* __restrict__ cnt)
{
    const int b = blockIdx.y;
    const int tid = threadIdx.x;
    const int q = blockIdx.x * 512 + tid;   // float4 index within batch

    __shared__ int lhist[2048];
    __shared__ int lcnt[16];
    for (int i = tid; i < 2048; i += 256) lhist[i] = 0;
    if (tid < 16) lcnt[tid] = 0;
    __syncthreads();

    const float4* pb = (const float4*)(proba + ((size_t)b * C_) * V_) + q;
    const float4* yb = (const float4*)(y     + ((size_t)b * C_) * V_) + q;
    const int s4 = V_ >> 2;                 // float4 stride between c-rows

    float4 p0 = pb[0], p1 = pb[256];        // c = 0 product init
    int4 l0 = make_int4(0, 0, 0, 0);        // label stays 0 if hot at c=0
    int4 l1 = make_int4(0, 0, 0, 0);

    #pragma unroll
    for (int c = 1; c < C_; c++) {
        float4 a0 = pb[c * s4], a1 = pb[c * s4 + 256];
        float4 q0 = yb[c * s4], q1 = yb[c * s4 + 256];
        p0.x *= a0.x; p0.y *= a0.y; p0.z *= a0.z; p0.w *= a0.w;
        p1.x *= a1.x; p1.y *= a1.y; p1.z *= a1.z; p1.w *= a1.w;
        if (q0.x > 0.f) l0.x = c;
        if (q0.y > 0.f) l0.y = c;
        if (q0.z > 0.f) l0.z = c;
        if (q0.w > 0.f) l0.w = c;
        if (q1.x > 0.f) l1.x = c;
        if (q1.y > 0.f) l1.y = c;
        if (q1.z > 0.f) l1.z = c;
        if (q1.w > 0.f) l1.w = c;
    }

    float4* wout = (float4*)(weights + (size_t)b * V_);
    wout[q] = p0; wout[q + 256] = p1;
    uchar4* lout = (uchar4*)(labels + (size_t)b * V_);
    lout[q]       = make_uchar4((unsigned char)l0.x, (unsigned char)l0.y,
                                (unsigned char)l0.z, (unsigned char)l0.w);
    lout[q + 256] = make_uchar4((unsigned char)l1.x, (unsigned char)l1.y,
                                (unsigned char)l1.z, (unsigned char)l1.w);

    float wv[8] = {p0.x, p0.y, p0.z, p0.w, p1.x, p1.y, p1.z, p1.w};
    int   lv[8] = {l0.x, l0.y, l0.z, l0.w, l1.x, l1.y, l1.z, l1.w};
    #pragma unroll
    for (int j = 0; j < 8; j++) {
        atomicAdd(&lcnt[lv[j]], 1);
        atomicAdd(&lhist[__float_as_uint(wv[j]) >> 21], 1);
    }
    __syncthreads();
    if (tid < 16) atomicAdd(&cnt[tid], lcnt[tid]);
    for (int i = tid; i < 2048; i += 256)
        if (lhist[i]) atomicAdd(&hist[b * 2048 + i], lhist[i]);
}

// K2 LDS-RMW: sums[c][f] = sum_v emb[b][f][v] * [label==c].
// The ~100 us was half VALU: select-add = 48 lane-ops/element (16 cmp+cndmask+add)
// = 42 us chip-wide, poorly overlapped with ~40 us memory. Replace with O(1)
// per element: PLAIN (non-atomic) LDS read-modify-write into per-thread private
// slots lacc[tid*17 + label] — ds_read + v_add + ds_write, bank-parallel
// (~6 cy/wave-op vs the 205 cy/wave-op divergent-ATOMIC pipe of R0-R3).
// Per-wave in-order LDS execution makes same-address RMW within a thread safe.
// Memory structure = R5's proven-null-risk schedule: one block per (seg, f, b),
// contiguous 128 KB stream, 8-deep float4 MLP, 18.4 KB LDS -> 8 blocks/CU.
__global__ __launch_bounds__(256) void k_sums(const float* __restrict__ emb,
                                              const unsigned char* __restrict__ labels,
                                              float* __restrict__ sums)
{
    __shared__ float lacc[256 * 17];
    __shared__ float part[256];
    const int tid = threadIdx.x;
    float* my = &lacc[tid * 17];
    #pragma unroll
    for (int c = 0; c < 16; c++) my[c] = 0.f;

    const int seg = blockIdx.x;             // 0..SEG_-1
    const int f   = blockIdx.y;             // 0..63
    const int b   = blockIdx.z;             // 0..3
    const int vlen = V_ / SEG_;             // 32768 voxels = 8192 float4

    const float4* src = (const float4*)(emb + (((size_t)b << 6) + f) * V_
                                        + (size_t)seg * vlen);
    const unsigned int* lb = (const unsigned int*)(labels + (size_t)b * V_
                                                   + (size_t)seg * vlen);

    // 8192 float4 / (256 threads * 8 groups) = 4 outer iterations
    for (int it = 0; it < 4; it++) {
        float4 v[8];
        unsigned lu[8];
        #pragma unroll
        for (int g = 0; g < 8; g++) {
            const int i4 = it * 2048 + g * 256 + tid;
            v[g]  = src[i4];
            lu[g] = lb[i4];
        }
        __builtin_amdgcn_sched_barrier(0);   // keep the 16 loads clustered (MLP)
        #pragma unroll
        for (int g = 0; g < 8; g++) {
            my[ lu[g]        & 0xff] += v[g].x;
            my[(lu[g] >>  8) & 0xff] += v[g].y;
            my[(lu[g] >> 16) & 0xff] += v[g].z;
            my[ lu[g] >> 24        ] += v[g].w;
        }
    }
    __syncthreads();

    // reduce 256x16 -> 16
    {
        const int c = tid & 15, r0 = (tid >> 4) << 4;
        float s = 0.f;
        #pragma unroll
        for (int i = 0; i < 16; i++) s += lacc[(r0 + i) * 17 + c];
        part[tid] = s;
    }
    __syncthreads();
    if (tid < 16) {
        float s = 0.f;
        #pragma unroll
        for (int j = 0; j < 16; j++) s += part[j * 16 + tid];
        atomicAdd(&sums[(tid << 6) + f], s);
    }
}

// K4 (absorbs K3): recompute per-batch threshold bin T from the L2-resident
// 8 KB histogram inside every block, then collect candidates with bin >= T.
__global__ __launch_bounds__(256) void k_collect(const float* __restrict__ weights,
                                                 const int* __restrict__ hist,
                                                 int* __restrict__ ccnt,
                                                 float* __restrict__ cval,
                                                 int* __restrict__ cidx)
{
    const int b = blockIdx.y;
    const int tid = threadIdx.x;
    __shared__ int part[256];
    __shared__ int suf[257];
    __shared__ int sT;

    const int* h = hist + b * 2048;
    int loc[8]; int s = 0;
    #pragma unroll
    for (int i = 0; i < 8; i++) { loc[i] = h[tid * 8 + i]; s += loc[i]; }
    part[tid] = s;
    __syncthreads();
    if (tid == 0) {
        suf[256] = 0;
        for (int t = 255; t >= 0; t--) suf[t] = suf[t + 1] + part[t];
    }
    __syncthreads();
    int cg[9];
    cg[8] = suf[tid + 1];
    #pragma unroll
    for (int i = 7; i >= 0; i--) cg[i] = cg[i + 1] + loc[i];
    #pragma unroll
    for (int i = 0; i < 8; i++)
        if (cg[i] >= K_ && cg[i + 1] < K_) sT = tid * 8 + i;
    __syncthreads();

    const unsigned T = (unsigned)sT;
    const int v = (blockIdx.x * 256 + tid) * 4;
    float4 w = *(const float4*)(weights + (size_t)b * V_ + v);
    float wv[4] = {w.x, w.y, w.z, w.w};
    for (int j = 0; j < 4; j++) {
        unsigned bits = __float_as_uint(wv[j]);
        if ((bits >> 21) >= T) {
            int p = atomicAdd(&ccnt[b], 1);
            if (p < CAP_) {
                cval[b * CAP_ + p] = wv[j];
                cidx[b * CAP_ + p] = v + j;
            }
        }
    }
}

// K5: exact top-K select, gather he/hec, build avg, pairwise contrastive loss.
__global__ __launch_bounds__(256) void k_final(const float* __restrict__ emb,
                                               const unsigned char* __restrict__ labels,
                                               const float* __restrict__ sums,
                                               const int* __restrict__ cnt,
                                               const int* __restrict__ ccnt,
                                               const float* __restrict__ cval,
                                               const int* __restrict__ cidx,
                                               float* __restrict__ out)
{
    const int b = blockIdx.x, tid = threadIdx.x;
    __shared__ float avg[1024];
    __shared__ float ec[K_ * 64];
    __shared__ float Ssum[K_ * 64];
    __shared__ float lsum[K_];
    __shared__ int selIdx[K_];
    __shared__ int selLab[K_];
    __shared__ int nk[16];
    __shared__ int lists[16 * K_];
    __shared__ int ofs[17];
    __shared__ float red[256];

    for (int i = tid; i < 1024; i += 256) {
        int c = i >> 6;
        float cn = (float)cnt[c];
        avg[i] = (cn > 0.f) ? 0.9f * sums[i] / fmaxf(cn, 1.f) : 0.f;
    }
    if (tid < K_) { lsum[tid] = 0.f; selIdx[tid] = 0; }
    if (tid < 16) nk[tid] = 0;

    int M = ccnt[b]; if (M > CAP_) M = CAP_;
    const float* cv = cval + b * CAP_;
    const int*   ci = cidx + b * CAP_;
    for (int i = tid; i < M; i += 256) {
        float v = cv[i]; int id = ci[i];
        int rank = 0;
        for (int j = 0; j < M; j++) {
            float vj = cv[j];
            rank += (vj > v) || (vj == v && ci[j] < id);
        }
        if (rank < K_) selIdx[rank] = id;
    }
    __syncthreads();
    for (int i = tid; i < K_; i += 256) selLab[i] = labels[(size_t)b * V_ + selIdx[i]];
    __syncthreads();
    if (tid == 0) {
        for (int i = 0; i < K_; i++) { int c = selLab[i]; lists[c * K_ + nk[c]] = i; nk[c]++; }
        int o = 0;
        for (int c = 0; c < 16; c++) { ofs[c] = o; o += nk[c] * nk[c]; }
        ofs[16] = o;
    }
    __syncthreads();

    for (int e = tid; e < K_ * 64; e += 256) {
        int k = e >> 6, f = e & 63;
        float h = emb[(((size_t)b << 6) + f) * V_ + selIdx[k]];
        int lab = selLab[k];
        float s = 0.f, ev = 0.f, lvv = 0.f;
        for (int c = 0; c < 16; c++) {
            float l = h * avg[(c << 6) + f] / 0.1f;
            float x = expf(l);
            s += x;
            if (c == lab) { ev = x; lvv = l; }
        }
        ec[e] = ev; Ssum[e] = s;
        atomicAdd(&lsum[k], lvv);
    }
    __syncthreads();

    const int P = ofs[16];
    float accv = 0.f;
    for (int p = tid; p < P; p += 256) {
        int c = 0;
        while (p >= ofs[c + 1]) c++;
        int loc = p - ofs[c];
        int n = nk[c];
        int i = lists[c * K_ + loc / n];
        int j = lists[c * K_ + loc % n];
        const float* eci = &ec[i << 6];
        const float* ecj = &ec[j << 6];
        const float* sj  = &Ssum[j << 6];
        float s = 0.f;
        for (int f = 0; f < 64; f++) s += logf(eci[f] + sj[f] - ecj[f]);
        accv += s / ((float)n * (float)n * 64.f);
    }
    for (int i2 = tid; i2 < K_; i2 += 256) {
        int c = selLab[i2];
        accv -= lsum[i2] / ((float)nk[c] * 64.f);
    }
    red[tid] = accv;
    __syncthreads();
    for (int s2 = 128; s2 > 0; s2 >>= 1) {
        if (tid < s2) red[tid] += red[tid + s2];
        __syncthreads();
    }
    if (tid == 0) atomicAdd(out, -red[0] / (float)B_);
}

extern "C" void kernel_launch(void* const* d_in, const int* in_sizes, int n_in,
                              void* d_out, int out_size, void* d_ws, size_t ws_size,
                              hipStream_t stream) {
    const float* proba = (const float*)d_in[0];
    const float* y     = (const float*)d_in[1];
    const float* emb   = (const float*)d_in[2];
    char* ws = (char*)d_ws;

    float* weights        = (float*)(ws + OFF_WEIGHTS);
    unsigned char* labels = (unsigned char*)(ws + OFF_LABELS);
    int* hist             = (int*)(ws + OFF_HIST);
    int* cnt              = (int*)(ws + OFF_CNT);
    float* sums           = (float*)(ws + OFF_SUMS);
    int* ccnt             = (int*)(ws + OFF_CCNT);
    float* cval           = (float*)(ws + OFF_CVAL);
    int* cidx             = (int*)(ws + OFF_CIDX);
    float* out            = (float*)d_out;

    hipMemsetAsync(ws + OFF_ZERO, 0, ZERO_BYTES, stream);
    hipMemsetAsync(out, 0, sizeof(float), stream);

    k_stream<<<dim3(V_ / 2048, B_), 256, 0, stream>>>(proba, y, weights, labels, hist, cnt);
    k_sums<<<dim3(SEG_, F_, B_), 256, 0, stream>>>(emb, labels, sums);
    k_collect<<<dim3(V_ / 1024, B_), 256, 0, stream>>>(weights, hist, ccnt, cval, cidx);
    k_final<<<B_, 256, 0, stream>>>(emb, labels, sums, cnt, ccnt, cval, cidx, out);
}